// Round 15
// baseline (189.343 us; speedup 1.0000x reference)
//
#include <hip/hip_runtime.h>
#include <math.h>

// SDN room acoustics: B=4 independent sims, one 256-thread block (4 waves) each.
// Lane layout (8-aligned node groups, bpermute-free):
//   lane 8n+j, j<5 : line PERM-source reader for line i=n*5+j (node n)
//   lane 8n+5     : mic FIR row of node n
//   lane 6        : direct src->mic path (group-0 pad; butterfly weight 0)
//   other pads    : idle (weights 0, read dummy row broadcast)
// Line permutation folded into the ring READ; p_i = FIR + inj is lane-local.
// Per-node dots via DPP butterflies (pure VALU). FIR in direct form.
// x is read from GLOBAL (L1/L2-resident, 16KB) -> zero DS traffic for x.
//
// BANK EQUALIZATION: per-row rotation puts each row's single reader at bank
// (reader_lane & 31); static because batch advance rotates banks uniformly
// (+28 mod 32) and LCAP == 0 mod 32.
//
// PAIR BARRIER SCHEME (one __syncthreads per 2 batches):
//   - line rows are the only cross-lane rows; D_line >= 58 (adjacent-wall
//     nodes >= 1.25 m apart with src/mic in the central box) => reads for
//     batch m touch only data of batches <= m-2.
//   - mic rows are same-lane read-after-write (in-order DS) for any D.
//   => prefetch for odd batch m issues mid-pair (after even batch's writes),
//      safe via the barrier that preceded batch m-1; prefetch for even batch
//      issues post-barrier (unconditionally safe, D >= 29).

#define NN    6
#define NLn   30
#define FIRN  7
#define TLEN  4000
#define LCAP  448                 // ring capacity: 16*BATCH, == 0 mod 32
#define EXT   13                  // mirror extension (reads reach LCAP+12)
#define HEAD  32                  // per-row rotation headroom
#define RSTRA (LCAP + EXT + HEAD) // 493
#define NROW  37                  // 30 line rows + 6 mic rows + 1 dummy
#define BATCH 28
#define SPW   7                   // steps per wave
#define NU    (SPW + FIRN)        // 14 ring reads per batch per lane

template<int CTRL>
__device__ __forceinline__ float dpp_add(float x) {
    int m = __builtin_amdgcn_update_dpp(0, __float_as_int(x), CTRL, 0xF, 0xF, false);
    return x + __int_as_float(m);
}
// value from lane i^4 within each 8-lane group:
//   row_shr:4 writes dest banks 1,3 ; row_shl:4 writes dest banks 0,2
__device__ __forceinline__ float dpp_xquad(float x) {
    int xi = __float_as_int(x);
    int m = __builtin_amdgcn_update_dpp(0, xi, 0x114, 0xF, 0xA, false); // row_shr:4
    m     = __builtin_amdgcn_update_dpp(m, xi, 0x104, 0xF, 0x5, false); // row_shl:4
    return __int_as_float(m);
}

__global__ __launch_bounds__(256, 1)
void sdn_kernel(const float* __restrict__ x, const float* __restrict__ srcp,
                const float* __restrict__ micp, const float* __restrict__ jf,
                const float* __restrict__ jv, const float* __restrict__ pw,
                float* __restrict__ out, int T)
{
    const int b   = blockIdx.x;
    const int l   = threadIdx.x;
    const int wl  = l & 63;
    const int wid = l >> 6;

    __shared__ float  rows[NROW][RSTRA];
    __shared__ float  st[NN + 1][29];        // mic staging [row][step]
    __shared__ double nds[NN][3];
    __shared__ int    sshift[NROW];

    for (int i = l; i < NROW * RSTRA; i += 256) (&rows[0][0])[i] = 0.f;

    const double room[3] = {4.0, 3.0, 2.5};
    double src[3] = {srcp[0], srcp[1], srcp[2]};
    double mic[3] = {micp[3*b+0], micp[3*b+1], micp[3*b+2]};

    if (l < NN) {
        int a = l >> 1;
        double w = (l & 1) ? room[a] : 0.0;
        double sa = (a == 0) ? src[0] : ((a == 1) ? src[1] : src[2]);
        double ma = (a == 0) ? mic[0] : ((a == 1) ? mic[1] : mic[2]);
        double ia = 2.0 * w - sa;
        double img0 = src[0], img1 = src[1], img2 = src[2];
        if (a == 0) img0 = ia; else if (a == 1) img1 = ia; else img2 = ia;
        double t = (w - ia) / (ma - ia);
        nds[l][0] = img0 + t * (mic[0] - img0);
        nds[l][1] = img1 + t * (mic[1] - img1);
        nds[l][2] = img2 + t * (mic[2] - img2);
    }
    __syncthreads();

    const double G = 343.0 / 16000.0;
    const int n  = (wl < 48) ? (wl >> 3) : 0;
    const int ir = wl & 7;
    const bool isline = (wl < 48) && (ir < 5);
    const bool ismic  = (wl < 48) && (ir == 5);
    const bool isdir  = (wl == 6);

    const int lineid = n * 5 + ir;                       // valid when isline
    #define PERMF(i) ((6*((i)+1) - ((i)%6) - 1) % NLn)
    const int srcl = PERMF(lineid % NLn);                // source line we read
    #undef PERMF
    const int ns = srcl / 5;                             // source line's node

    // own-node geometry (inj, micg, uu)
    double dx = nds[n][0] - src[0], dy = nds[n][1] - src[1], dz = nds[n][2] - src[2];
    double dsn = sqrt(dx*dx + dy*dy + dz*dz);
    dx = nds[n][0] - mic[0]; dy = nds[n][1] - mic[1]; dz = nds[n][2] - mic[2];
    double dnm = sqrt(dx*dx + dy*dy + dz*dz);
    dx = mic[0] - src[0]; dy = mic[1] - src[1]; dz = mic[2] - src[2];
    double dsm = sqrt(dx*dx + dy*dy + dz*dz);

    const int   Dsn  = (int)rint(dsn / G);
    const int   Dsm  = (int)rint(dsm / G);
    const float srcg = (float)(0.5 * G / dsn);
    const float micg = (float)(1.0 / (1.0 + dnm / dsn));
    const float dirg = (float)(1.0 / dsm);

    // delay of the row this lane READS
    int Dline;
    {
        int mm = srcl % 5;
        int m2 = mm + (mm >= ns ? 1 : 0);                // PAIRS of source line
        double ax = nds[ns][0] - nds[m2][0];
        double ay = nds[ns][1] - nds[m2][1];
        double az = nds[ns][2] - nds[m2][2];
        Dline = (int)rint(sqrt(ax*ax + ay*ay + az*az) / G);
    }
    const int Dmic = (int)rint(dnm / G);
    const int D = isline ? Dline : (ismic ? Dmic : 64);

    // injection gain and x-delay for this lane
    float srcgl; int Dxl;
    if (isline || ismic) { srcgl = srcg; Dxl = Dsn; }
    else if (isdir)      { srcgl = dirg; Dxl = Dsm; }
    else                 { srcgl = 0.f;  Dxl = 0;   }

    // FIR coefficients: node of the row we read (source line's node / own node)
    const int nc = isline ? ns : n;
    const bool hasfir = isline || ismic;
    float c0,c1,c2,c3,c4,c5,c6,c7;
    {
        const float* f = jf + nc*(FIRN+1);
        c0 = hasfir ? f[7] : 0.f; c1 = hasfir ? f[6] : 0.f;
        c2 = hasfir ? f[5] : 0.f; c3 = hasfir ? f[4] : 0.f;
        c4 = hasfir ? f[3] : 0.f; c5 = hasfir ? f[2] : 0.f;
        c6 = hasfir ? f[1] : 0.f; c7 = hasfir ? f[0] : 0.f;
    }

    // butterfly weights and write-value constants
    const float uu = jv[n*5+0]*jv[n*5+0] + jv[n*5+1]*jv[n*5+1] + jv[n*5+2]*jv[n*5+2]
                   + jv[n*5+3]*jv[n*5+3] + jv[n*5+4]*jv[n*5+4];
    const float c2u = 2.0f / uu;
    const float vw = isline ? jv[n*5+ir] : 0.f;                  // v_j weight
    const float qw = isline ? micg * pw[n*5+ir] : 0.f;           // micg*q_j weight
    float Wa;
    if (isline) Wa = vw;
    else if (ismic) {
        Wa = micg * (jv[n*5+0]*pw[n*5+0] + jv[n*5+1]*pw[n*5+1] + jv[n*5+2]*pw[n*5+2]
                   + jv[n*5+3]*pw[n*5+3] + jv[n*5+4]*pw[n*5+4]);
    } else Wa = 0.f;

    // row ids
    const int rdrow = isline ? srcl : (ismic ? NLn + n : NROW - 1);
    const int wrrow = isline ? lineid : (ismic ? NLn + n : NROW - 1);
    const bool haswrite = isline || ismic;
    const bool hasstage = ismic || isdir;

    const int k0off = SPW * wid;                 // 0,7,14,21
    const int shift = isline ? 8 : 7;            // u window: k0-shift-D+j

    // ---- per-row bank rotation: reader bank == (reader lane & 31) ----
    if (wid == 0) {
        if (isline || ismic) {
            int v = ((wl & 31) - rdrow * RSTRA + shift + D) % 32;
            sshift[rdrow] = (v + 32) % 32;
        }
        if (l == 0) {
            int v = (6 - (NROW-1) * RSTRA + 7 + 64) % 32;
            sshift[NROW-1] = (v + 32) % 32;
        }
    }
    __syncthreads();

    float* rdbase = &rows[rdrow][0] + sshift[rdrow];
    float* wrbase = &rows[wrrow][0] + sshift[wrrow];
    float* strow  = st[ismic ? n : 6];
    float* outp = out + b * T;

    int cur_off = ((k0off - shift - D) % LCAP + LCAP) % LCAP;
    int wp0 = 0;
    const int NPAIR = ((T + BATCH - 1) / BATCH + 1) / 2;   // 72 for T=4000

    float u[NU], xq[SPW], u2[NU], xq2[SPW];

    // prefetch macros (arrays are unroll-indexed -> stay in VGPRs)
    #define PREF(U, XQ, TB) do {                                        \
        _Pragma("unroll")                                               \
        for (int j = 0; j < NU; ++j) (U)[j] = rdbase[cur_off + j];      \
        _Pragma("unroll")                                               \
        for (int i = 0; i < SPW; ++i) {                                 \
            int gk = (TB) + k0off + i - Dxl;                            \
            int ck = gk < 0 ? 0 : (gk >= T ? T - 1 : gk);               \
            float xv = x[ck];                                           \
            (XQ)[i] = (gk < 0 || gk >= T) ? 0.f : xv;                   \
        }                                                               \
        cur_off += BATCH; if (cur_off >= LCAP) cur_off -= LCAP;         \
    } while (0)

    #define BODY(U, XQ, WPS) do {                                       \
        float fir[SPW], inj[SPW], p[SPW];                               \
        _Pragma("unroll")                                               \
        for (int i = 0; i < SPW; ++i) {                                 \
            float a = c7 * (U)[i];                                      \
            a = fmaf(c6, (U)[i+1], a); a = fmaf(c5, (U)[i+2], a);       \
            a = fmaf(c4, (U)[i+3], a); a = fmaf(c3, (U)[i+4], a);       \
            a = fmaf(c2, (U)[i+5], a); a = fmaf(c1, (U)[i+6], a);       \
            a = fmaf(c0, (U)[i+7], a);                                  \
            inj[i] = srcgl * (XQ)[i];                                   \
            if (isdir) a = inj[i];                                      \
            fir[i] = a;                                                 \
            p[i] = a + inj[i];                                          \
        }                                                               \
        float wv[SPW];                                                  \
        _Pragma("unroll")                                               \
        for (int i = 0; i < SPW; ++i) {                                 \
            float tv = vw * p[i];                                       \
            float tq = qw * p[i];                                       \
            tv = dpp_add<0xB1>(tv); tq = dpp_add<0xB1>(tq);             \
            tv = dpp_add<0x4E>(tv); tq = dpp_add<0x4E>(tq);             \
            float Av = tv + dpp_xquad(tv);                              \
            float Bv = tq + dpp_xquad(tq);                              \
            float s  = Av * c2u;                                        \
            wv[i] = fmaf(s, Wa, -(ismic ? Bv : p[i]));                  \
        }                                                               \
        if (haswrite) {                                                 \
            _Pragma("unroll")                                           \
            for (int i = 0; i < SPW; ++i) wrbase[(WPS) + k0off + i] = wv[i]; \
        }                                                               \
        if ((WPS) == 0) {                                               \
            if (haswrite) {                                             \
                _Pragma("unroll")                                       \
                for (int i = 0; i < SPW; ++i)                           \
                    if (k0off + i < EXT) wrbase[LCAP + k0off + i] = wv[i]; \
            }                                                           \
        }                                                               \
        if (hasstage) {                                                 \
            _Pragma("unroll")                                           \
            for (int i = 0; i < SPW; ++i) strow[k0off + i] = fir[i];    \
        }                                                               \
    } while (0)

    #define FOUT(T0) do {                                               \
        if (wl < SPW) {                                                 \
            int col  = k0off + wl;                                      \
            int gidx = (T0) * BATCH + col;                              \
            if (gidx < T) {                                             \
                float ssum = ((st[0][col] + st[1][col]) + (st[2][col] + st[3][col])) \
                           + ((st[4][col] + st[5][col]) + st[6][col]);  \
                outp[gidx] = ssum;                                      \
            }                                                           \
        }                                                               \
    } while (0)

    // prologue: prefetch batch 0 (ring zero-initialized; x clamped/masked)
    PREF(u, xq, 0);

    for (int pzz = 0; pzz < NPAIR; ++pzz) {
        const int t0 = 2 * pzz;
        // ---- even batch t0 ----
        BODY(u, xq, wp0);
        // mid-pair prefetch for odd batch t0+1: no barrier needed —
        // lines D>=58 target data <= t0-2 (visible via barrier before t0);
        // mic rows same-lane in-order after this wave's writes above.
        PREF(u2, xq2, (t0 + 1) * BATCH);
        FOUT(t0);

        int wp1 = wp0 + BATCH; if (wp1 >= LCAP) wp1 -= LCAP;
        // ---- odd batch t0+1 ----
        BODY(u2, xq2, wp1);
        __syncthreads();                      // writes(t0,t0+1) visible
        // post-barrier prefetch for even batch t0+2 (unconditionally safe)
        PREF(u, xq, (t0 + 2) * BATCH);
        FOUT(t0 + 1);

        wp0 = wp1 + BATCH; if (wp0 >= LCAP) wp0 -= LCAP;
    }

    #undef PREF
    #undef BODY
    #undef FOUT
}

extern "C" void kernel_launch(void* const* d_in, const int* in_sizes, int n_in,
                              void* d_out, int out_size, void* d_ws, size_t ws_size,
                              hipStream_t stream)
{
    const float* x    = (const float*)d_in[0];
    const float* srcp = (const float*)d_in[1];
    const float* micp = (const float*)d_in[2];
    const float* jf   = (const float*)d_in[3];
    const float* jv   = (const float*)d_in[4];
    const float* pw   = (const float*)d_in[5];
    float* out = (float*)d_out;

    int T  = in_sizes[0];
    if (T > TLEN) T = TLEN;
    int Bc = in_sizes[2] / 3;

    sdn_kernel<<<Bc, 256, 0, stream>>>(x, srcp, micp, jf, jv, pw, out, T);
}

// Round 16
// 86.556 us; speedup vs baseline: 2.1875x; 2.1875x over previous
//
#include <hip/hip_runtime.h>
#include <math.h>

// SDN room acoustics: B=4 independent sims, one 512-thread block (8 waves) each.
// Per-wave lane layout (8-aligned node groups, bpermute-free):
//   lane 8n+j, j<5 : line PERM-source reader for line i=n*5+j (node n)
//   lane 8n+5     : mic FIR row of node n
//   lane 6        : direct src->mic path (group-0 pad; butterfly weight 0)
//   other pads    : idle (weights 0, read dummy row broadcast)
// Wave w owns steps [mB+7w, mB+7w+6] of each B=56 batch (butterfly/ring).
// Line permutation folded into the ring READ; p_i = FIR + inj is lane-local.
// Per-node dots via DPP butterflies (pure VALU). FIR in direct form.
//
// LAGGED MIC PIPELINE: mic/dir lanes' butterfly role (receive Av/Bv, ring
// write) is step-synced, but their FIR-read + output staging is INDEPENDENT
// (mic inj is dead: mic butterfly weights are 0). Mic/dir process their FIR
// one batch lagged: at batch m they emit outputs for steps (m-1)B+..., whose
// ring reads target positions <= mB+55 (any D>=0) - always visible after the
// single per-batch barrier. Line prefetch for batch m+1 is safe post-barrier
// because D_line >= 58 >= 55 (nodes on different walls, src/mic central =>
// adjacent-wall node distance >= 1.25 m).
//
// BANK EQUALIZATION: per-row rotation puts each row's single reader at bank
// (reader_lane & 31); static because batch advance rotates banks uniformly
// (+56 == +24 mod 32) and LCAP == 0 mod 32. Mic rows fold the lag (+B) in.

#define NN    6
#define NLn   30
#define FIRN  7
#define TLEN  4000
#define LCAP  448                 // ring capacity: 8*BATCH, == 0 mod 32
#define EXT   13                  // mirror extension (reads reach LCAP+12)
#define HEAD  32                  // per-row rotation headroom
#define RSTRA (LCAP + EXT + HEAD) // 493
#define PADX  264                 // zero prefix: x[k-D] needs no bounds check
#define XPAD  64                  // zero tail for the final flush batch
#define NROW  37                  // 30 line rows + 6 mic rows + 1 dummy
#define BATCH 56
#define SPW   7                   // steps per wave
#define NU    (SPW + FIRN)        // 14 ring reads per batch per lane

template<int CTRL>
__device__ __forceinline__ float dpp_add(float x) {
    int m = __builtin_amdgcn_update_dpp(0, __float_as_int(x), CTRL, 0xF, 0xF, false);
    return x + __int_as_float(m);
}
// value from lane i^4 within each 8-lane group:
//   row_shr:4 writes dest banks 1,3 ; row_shl:4 writes dest banks 0,2
__device__ __forceinline__ float dpp_xquad(float x) {
    int xi = __float_as_int(x);
    int m = __builtin_amdgcn_update_dpp(0, xi, 0x114, 0xF, 0xA, false); // row_shr:4
    m     = __builtin_amdgcn_update_dpp(m, xi, 0x104, 0xF, 0x5, false); // row_shl:4
    return __int_as_float(m);
}

__global__ __launch_bounds__(512)
void sdn_kernel(const float* __restrict__ x, const float* __restrict__ srcp,
                const float* __restrict__ micp, const float* __restrict__ jf,
                const float* __restrict__ jv, const float* __restrict__ pw,
                float* __restrict__ out, int T)
{
    const int b   = blockIdx.x;
    const int l   = threadIdx.x;
    const int wl  = l & 63;
    const int wid = l >> 6;                  // 0..7

    __shared__ float  rows[NROW][RSTRA];
    __shared__ float  xl[PADX + TLEN + XPAD];
    __shared__ float  st[NN + 1][BATCH + 1]; // mic staging [row][step], stride 57
    __shared__ double nds[NN][3];
    __shared__ int    sshift[NROW];

    for (int i = l; i < NROW * RSTRA;       i += 512) (&rows[0][0])[i] = 0.f;
    for (int i = l; i < PADX + TLEN + XPAD; i += 512) xl[i] = 0.f;
    __syncthreads();
    for (int i = l; i < T; i += 512) xl[PADX + i] = x[i];

    const double room[3] = {4.0, 3.0, 2.5};
    double src[3] = {srcp[0], srcp[1], srcp[2]};
    double mic[3] = {micp[3*b+0], micp[3*b+1], micp[3*b+2]};

    if (l < NN) {
        int a = l >> 1;
        double w = (l & 1) ? room[a] : 0.0;
        double sa = (a == 0) ? src[0] : ((a == 1) ? src[1] : src[2]);
        double ma = (a == 0) ? mic[0] : ((a == 1) ? mic[1] : mic[2]);
        double ia = 2.0 * w - sa;
        double img0 = src[0], img1 = src[1], img2 = src[2];
        if (a == 0) img0 = ia; else if (a == 1) img1 = ia; else img2 = ia;
        double t = (w - ia) / (ma - ia);
        nds[l][0] = img0 + t * (mic[0] - img0);
        nds[l][1] = img1 + t * (mic[1] - img1);
        nds[l][2] = img2 + t * (mic[2] - img2);
    }
    __syncthreads();

    const double G = 343.0 / 16000.0;
    const int n  = (wl < 48) ? (wl >> 3) : 0;
    const int ir = wl & 7;
    const bool isline = (wl < 48) && (ir < 5);
    const bool ismic  = (wl < 48) && (ir == 5);
    const bool isdir  = (wl == 6);

    const int lineid = n * 5 + ir;                       // valid when isline
    #define PERMF(i) ((6*((i)+1) - ((i)%6) - 1) % NLn)
    const int srcl = PERMF(lineid % NLn);                // source line we read
    #undef PERMF
    const int ns = srcl / 5;                             // source line's node

    // own-node geometry (inj, micg, uu)
    double dx = nds[n][0] - src[0], dy = nds[n][1] - src[1], dz = nds[n][2] - src[2];
    double dsn = sqrt(dx*dx + dy*dy + dz*dz);
    dx = nds[n][0] - mic[0]; dy = nds[n][1] - mic[1]; dz = nds[n][2] - mic[2];
    double dnm = sqrt(dx*dx + dy*dy + dz*dz);
    dx = mic[0] - src[0]; dy = mic[1] - src[1]; dz = mic[2] - src[2];
    double dsm = sqrt(dx*dx + dy*dy + dz*dz);

    const int   Dsn  = (int)rint(dsn / G);
    const int   Dsm  = (int)rint(dsm / G);
    const float srcg = (float)(0.5 * G / dsn);
    const float micg = (float)(1.0 / (1.0 + dnm / dsn));
    const float dirg = (float)(1.0 / dsm);

    // delay of the row this lane READS
    int Dline;
    {
        int mm = srcl % 5;
        int m2 = mm + (mm >= ns ? 1 : 0);                // PAIRS of source line
        double ax = nds[ns][0] - nds[m2][0];
        double ay = nds[ns][1] - nds[m2][1];
        double az = nds[ns][2] - nds[m2][2];
        Dline = (int)rint(sqrt(ax*ax + ay*ay + az*az) / G);
    }
    const int Dmic = (int)rint(dnm / G);
    const int D = isline ? Dline : (ismic ? Dmic : 64);

    // injection gain + x pointer offset (dir is LAGGED by one batch)
    float srcgl; int xoff;
    if (isline)      { srcgl = srcg; xoff = PADX - Dsn; }
    else if (isdir)  { srcgl = dirg; xoff = PADX - Dsm - BATCH; }
    else             { srcgl = 0.f;  xoff = PADX; }      // mic inj is dead

    // FIR coefficients: node of the row we read (source line's node / own node)
    const int nc = isline ? ns : n;
    const bool hasfir = isline || ismic;
    float c0,c1,c2,c3,c4,c5,c6,c7;
    {
        const float* f = jf + nc*(FIRN+1);
        c0 = hasfir ? f[7] : 0.f; c1 = hasfir ? f[6] : 0.f;
        c2 = hasfir ? f[5] : 0.f; c3 = hasfir ? f[4] : 0.f;
        c4 = hasfir ? f[3] : 0.f; c5 = hasfir ? f[2] : 0.f;
        c6 = hasfir ? f[1] : 0.f; c7 = hasfir ? f[0] : 0.f;
    }

    // butterfly weights and write-value constants
    const float uu = jv[n*5+0]*jv[n*5+0] + jv[n*5+1]*jv[n*5+1] + jv[n*5+2]*jv[n*5+2]
                   + jv[n*5+3]*jv[n*5+3] + jv[n*5+4]*jv[n*5+4];
    const float c2u = 2.0f / uu;
    const float vw = isline ? jv[n*5+ir] : 0.f;                  // v_j weight
    const float qw = isline ? micg * pw[n*5+ir] : 0.f;           // micg*q_j weight
    float Wa;
    if (isline) Wa = vw;
    else if (ismic) {
        Wa = micg * (jv[n*5+0]*pw[n*5+0] + jv[n*5+1]*pw[n*5+1] + jv[n*5+2]*pw[n*5+2]
                   + jv[n*5+3]*pw[n*5+3] + jv[n*5+4]*pw[n*5+4]);
    } else Wa = 0.f;

    // row ids
    const int rdrow = isline ? srcl : (ismic ? NLn + n : NROW - 1);
    const int wrrow = isline ? lineid : (ismic ? NLn + n : NROW - 1);
    const bool haswrite = isline || ismic;
    const bool hasstage = ismic || isdir;

    const int k0off = SPW * wid;                 // 0,7,...,49
    const int shift = isline ? 8 : 7;            // u window: k0-shift-D+j
    const int lag   = isline ? 0 : BATCH;        // mic/dir/pads read lagged

    // ---- per-row bank rotation: reader bank == (reader lane & 31) ----
    // reader offset includes -lag, so fold +lag into the rotation.
    if (wid == 0) {
        if (isline || ismic) {
            int v = ((wl & 31) - rdrow * RSTRA + shift + D + lag) % 32;
            sshift[rdrow] = (v + 32) % 32;
        }
        if (l == 0) {   // dummy row (pads, dir): D=64, shift=7, lagged
            int v = (6 - (NROW-1) * RSTRA + 7 + 64 + BATCH) % 32;
            sshift[NROW-1] = (v + 32) % 32;
        }
    }
    __syncthreads();

    float* rdbase = &rows[rdrow][0] + sshift[rdrow];
    float* wrbase = &rows[wrrow][0] + sshift[wrrow];
    float* strow  = st[ismic ? n : 6];
    const float* xpc = xl + xoff;
    float* outp = out + b * T;

    int cur_off = ((k0off - shift - D - lag) % LCAP + LCAP) % LCAP;
    int wp0 = 0;
    const int NB = (T + BATCH - 1) / BATCH;      // 72 for T=4000

    float u[NU], xq[SPW];
    // prologue: prefetch batch 0 (ring zero-initialized; lagged reads hit zeros)
    #pragma unroll
    for (int j = 0; j < NU; ++j) u[j] = rdbase[cur_off + j];
    #pragma unroll
    for (int i = 0; i < SPW; ++i) xq[i] = xpc[k0off + i];
    cur_off += BATCH; if (cur_off >= LCAP) cur_off -= LCAP;

    for (int m = 0; m <= NB; ++m) {
        // ---- B: direct-form FIRs + injection -> p ----
        // line lanes: steps mB+k0off+i (butterfly-synced)
        // mic/dir:    steps (m-1)B+k0off+i (lagged output pipeline)
        float fir[SPW], inj[SPW], p[SPW];
        #pragma unroll
        for (int i = 0; i < SPW; ++i) {
            float a = c7 * u[i];
            a = fmaf(c6, u[i+1], a); a = fmaf(c5, u[i+2], a);
            a = fmaf(c4, u[i+3], a); a = fmaf(c3, u[i+4], a);
            a = fmaf(c2, u[i+5], a); a = fmaf(c1, u[i+6], a);
            a = fmaf(c0, u[i+7], a);
            inj[i] = srcgl * xq[i];
            if (isdir) a = inj[i];               // direct path (lagged x)
            fir[i] = a;
            p[i] = a + inj[i];
        }

        // ---- C: DPP butterflies -> A,B per group; write values ----
        float wv[SPW];
        #pragma unroll
        for (int i = 0; i < SPW; ++i) {
            float tv = vw * p[i];
            float tq = qw * p[i];
            tv = dpp_add<0xB1>(tv); tq = dpp_add<0xB1>(tq);  // quad xor1
            tv = dpp_add<0x4E>(tv); tq = dpp_add<0x4E>(tq);  // quad xor2
            float Av = tv + dpp_xquad(tv);                    // + other quad
            float Bv = tq + dpp_xquad(tq);
            float s  = Av * c2u;
            wv[i] = fmaf(s, Wa, -(ismic ? Bv : p[i]));
        }

        // ---- D: ring writes (+ mirror), mic staging (lagged steps) ----
        if (haswrite) {
            #pragma unroll
            for (int i = 0; i < SPW; ++i) wrbase[wp0 + k0off + i] = wv[i];
        }
        if (wp0 == 0) {                          // uniform, 1 in 8 batches
            if (haswrite) {
                #pragma unroll
                for (int i = 0; i < SPW; ++i)
                    if (k0off + i < EXT) wrbase[LCAP + k0off + i] = wv[i];
            }
        }
        if (hasstage) {
            #pragma unroll
            for (int i = 0; i < SPW; ++i) strow[k0off + i] = fir[i];
        }

        __syncthreads();                         // batch-m writes visible

        // ---- prefetch batch m+1 (post-barrier; line D>=58 => targets ----
        // ---- <= batch m; lagged mic/dir targets <= batch m trivially) ----
        if (m < NB) {
            #pragma unroll
            for (int j = 0; j < NU; ++j) u[j] = rdbase[cur_off + j];
            #pragma unroll
            for (int i = 0; i < SPW; ++i) xq[i] = xpc[(m+1)*BATCH + k0off + i];
            cur_off += BATCH; if (cur_off >= LCAP) cur_off -= LCAP;
        }

        // ---- F: lagged output (lanes 0..6 sum 7 staged rows, same wave) ----
        if (wl < SPW) {
            int col  = k0off + wl;
            int gidx = (m - 1) * BATCH + col;
            if ((unsigned)gidx < (unsigned)T) {
                float ssum = ((st[0][col] + st[1][col]) + (st[2][col] + st[3][col]))
                           + ((st[4][col] + st[5][col]) + st[6][col]);
                outp[gidx] = ssum;
            }
        }

        wp0 += BATCH; if (wp0 >= LCAP) wp0 -= LCAP;
    }
}

extern "C" void kernel_launch(void* const* d_in, const int* in_sizes, int n_in,
                              void* d_out, int out_size, void* d_ws, size_t ws_size,
                              hipStream_t stream)
{
    const float* x    = (const float*)d_in[0];
    const float* srcp = (const float*)d_in[1];
    const float* micp = (const float*)d_in[2];
    const float* jf   = (const float*)d_in[3];
    const float* jv   = (const float*)d_in[4];
    const float* pw   = (const float*)d_in[5];
    float* out = (float*)d_out;

    int T  = in_sizes[0];
    if (T > TLEN) T = TLEN;
    int Bc = in_sizes[2] / 3;

    sdn_kernel<<<Bc, 512, 0, stream>>>(x, srcp, micp, jf, jv, pw, out, T);
}